// Round 14
// baseline (109.913 us; speedup 1.0000x reference)
//
#include <hip/hip_runtime.h>
#include <hip/hip_bf16.h>
#include <cstdint>

typedef __bf16 bf16;
typedef __bf16 bf16x4 __attribute__((ext_vector_type(4)));
typedef __bf16 bf16x8 __attribute__((ext_vector_type(8)));
typedef float f32x4 __attribute__((ext_vector_type(4)));
typedef float f32x16 __attribute__((ext_vector_type(16)));
typedef unsigned int u32x4 __attribute__((ext_vector_type(4)));

#define DM   1024
#define SEQ  2048
#define NH   16
#define DKH  64

__device__ __forceinline__ bf16x8 ld8(const bf16* p) {
    return *reinterpret_cast<const bf16x8*>(p);
}

// async global->LDS, 16B per lane (wave-uniform LDS base + lane*16 layout)
__device__ __forceinline__ void gld16(const void* g, void* lds) {
    __builtin_amdgcn_global_load_lds(
        (__attribute__((address_space(1))) void*)(uintptr_t)g,
        (__attribute__((address_space(3))) void*)(uint32_t)(uintptr_t)lds,
        16, 0, 0);
}

__device__ __forceinline__ f32x4 mfma16(bf16x8 a, bf16x8 b, f32x4 c) {
    return __builtin_amdgcn_mfma_f32_16x16x32_bf16(a, b, c, 0, 0, 0);
}
__device__ __forceinline__ f32x16 mfma32(bf16x8 a, bf16x8 b, f32x16 c) {
    return __builtin_amdgcn_mfma_f32_32x32x16_bf16(a, b, c, 0, 0, 0);
}

// v_cvt_pk_bf16_f32: d[15:0]=bf16(lo), d[31:16]=bf16(hi)
__device__ __forceinline__ unsigned pkbf(float lo, float hi) {
    unsigned r;
    asm("v_cvt_pk_bf16_f32 %0, %1, %2" : "=v"(r) : "v"(lo), "v"(hi));
    return r;
}
// v_permlane32_swap_b32 a, b: a[hi lanes] <-> b[lo lanes]
__device__ __forceinline__ void plswap(unsigned& a, unsigned& b) {
    asm volatile("v_permlane32_swap_b32 %0, %1" : "+v"(a), "+v"(b));
}

// ---------------- fused fp32 -> bf16 casts (x + 4 weights, one launch) -------
__global__ __launch_bounds__(256) void cvt_all(
    const float4* __restrict__ x,  const float4* __restrict__ wq,
    const float4* __restrict__ wk, const float4* __restrict__ wv,
    const float4* __restrict__ wo,
    ushort4* __restrict__ xb,  ushort4* __restrict__ wqb,
    ushort4* __restrict__ wkb, ushort4* __restrict__ wvb,
    ushort4* __restrict__ wob) {
    int i = blockIdx.x * 256 + threadIdx.x;   // 2M float4 total
    const float4* src;
    ushort4* dst;
    int off;
    if (i < 1048576) {
        src = x; dst = xb; off = i;
    } else {
        int r = i - 1048576;
        int sel = r >> 18;          // 4 weight regions of 256K float4
        off = r & 262143;
        src = sel == 0 ? wq : sel == 1 ? wk : sel == 2 ? wv : wo;
        dst = sel == 0 ? wqb : sel == 1 ? wkb : sel == 2 ? wvb : wob;
    }
    float4 f = src[off];
    ushort4 u;
    u.x = __builtin_bit_cast(unsigned short, (bf16)f.x);
    u.y = __builtin_bit_cast(unsigned short, (bf16)f.y);
    u.z = __builtin_bit_cast(unsigned short, (bf16)f.z);
    u.w = __builtin_bit_cast(unsigned short, (bf16)f.w);
    dst[off] = u;
}

// ---------------- GEMM body: 128x128 tile, BK=32, 3-buffer counted-vmcnt -----
template <int OUT_MODE>
__device__ __forceinline__ void gemm_body(const bf16* __restrict__ A,
                                          const bf16* __restrict__ W,
                                          const float* __restrict__ bias,
                                          void* __restrict__ outp,
                                          int m0, int n0, float scale,
                                          bf16* __restrict__ S) {
    constexpr int BK = 32;           // 32 K-tiles of 32
    const int t    = threadIdx.x;
    const int lane = t & 63;
    const int r16  = lane & 15, grp = lane >> 4;
    const int wave = t >> 6;
    const int wr   = (wave >> 1) * 64;
    const int wc   = (wave & 1) * 64;

    f32x4 acc[4][4] = {};

    const int srow = t >> 2;         // 0..63
    const int scol = t & 3;          // 16B slot within 64B row

    auto STAGE = [&](int buf, int kt) {
#pragma unroll
        for (int i = 0; i < 2; ++i) {
            const int row = i * 64 + srow;                 // 0..127
            const int cs = (scol ^ (row & 3)) * 8;         // pre-swizzled col
            gld16(A + (size_t)(m0 + row) * DM + kt * BK + cs,
                  &S[buf * 8192 + i * 2048 + t * 8]);
            gld16(W + (size_t)(n0 + row) * DM + kt * BK + cs,
                  &S[buf * 8192 + 4096 + i * 2048 + t * 8]);
        }
    };

    STAGE(0, 0);
    STAGE(1, 1);

#pragma unroll
    for (int kt = 0; kt < 32; ++kt) {
        if (kt == 31) { asm volatile("s_waitcnt vmcnt(0)" ::: "memory"); }
        else          { asm volatile("s_waitcnt vmcnt(4)" ::: "memory"); }
        __builtin_amdgcn_sched_barrier(0);
        __builtin_amdgcn_s_barrier();
        __builtin_amdgcn_sched_barrier(0);

        if (kt < 30) STAGE((kt + 2) % 3, kt + 2);

        const bf16* Ab = &S[(kt % 3) * 8192];
        const bf16* Bb = Ab + 4096;
        bf16x8 af[4], bfr[4];
#pragma unroll
        for (int m = 0; m < 4; ++m) {
            const int row = wr + m * 16 + r16;
            af[m] = ld8(&Ab[row * BK + ((grp ^ (row & 3)) * 8)]);
        }
#pragma unroll
        for (int n = 0; n < 4; ++n) {
            const int row = wc + n * 16 + r16;
            bfr[n] = ld8(&Bb[row * BK + ((grp ^ (row & 3)) * 8)]);
        }
        __builtin_amdgcn_s_setprio(1);
#pragma unroll
        for (int m = 0; m < 4; ++m)
#pragma unroll
            for (int n = 0; n < 4; ++n)
                acc[m][n] = mfma16(af[m], bfr[n], acc[m][n]);
        __builtin_amdgcn_s_setprio(0);
    }

    if constexpr (OUT_MODE == 2) {
        // V^T epilogue: transpose 64x64 wave subtile via LDS (dead S space),
        // store coalesced 128B token-rows. (R7-proven pattern.)
        __syncthreads();
        bf16* Tw = &S[wave * 4096];
        const int b = m0 >> 11;
        const int tokbase = (m0 & 2047) + wr;
#pragma unroll
        for (int n = 0; n < 4; ++n) {
            const int dim = n * 16 + r16;            // local dim 0..63
            const float bvv = bias[n0 - 2048 + wc + dim];
#pragma unroll
            for (int m = 0; m < 4; ++m) {
                bf16x4 w4 = {(bf16)(acc[m][n][0] + bvv), (bf16)(acc[m][n][1] + bvv),
                             (bf16)(acc[m][n][2] + bvv), (bf16)(acc[m][n][3] + bvv)};
                const int slot = (m * 2 + (grp >> 1)) ^ (dim & 7);
                *reinterpret_cast<bf16x4*>(&Tw[dim * 64 + slot * 8 + (grp & 1) * 4]) = w4;
            }
        }
        asm volatile("" ::: "memory");
#pragma unroll
        for (int r = 0; r < 8; ++r) {
            const int dim = (lane >> 3) + 8 * r;
            const int ts  = lane & 7;
            bf16x8 v = ld8(&Tw[dim * 64 + ((ts ^ (dim & 7)) * 8)]);
            const int col = n0 - 2048 + wc + dim;    // global dim 0..1023
            bf16* dst = (bf16*)outp +
                ((size_t)(b * NH + (col >> 6)) * DKH + (col & 63)) * SEQ +
                tokbase + ts * 8;
            *reinterpret_cast<bf16x8*>(dst) = v;
        }
    } else {
#pragma unroll
        for (int n = 0; n < 4; ++n) {
            const int col = (OUT_MODE == 0 ? (n0 & 1023) : n0) + wc + n * 16 + r16;
            const float bvv = bias[col];
#pragma unroll
            for (int m = 0; m < 4; ++m) {
                const int row = m0 + wr + m * 16 + grp * 4;
#pragma unroll
                for (int j = 0; j < 4; ++j) {
                    float v = (acc[m][n][j] + bvv) * scale;
                    if constexpr (OUT_MODE == 1)
                        ((float*)outp)[(size_t)(row + j) * DM + col] = v;
                    else
                        ((bf16*)outp)[(size_t)(row + j) * DM + col] = (bf16)v;
                }
            }
        }
    }
}

// fused QKV: grid 768 (XCD-bijective), n-tiles 0..7=Q, 8..15=K, 16..23=V^T
__global__ __launch_bounds__(256, 3) void gemm_qkv(
    const bf16* __restrict__ xb, const bf16* __restrict__ wqkv,
    const float* __restrict__ bq, const float* __restrict__ bk,
    const float* __restrict__ bv_,
    bf16* __restrict__ q, bf16* __restrict__ k, bf16* __restrict__ vt) {
    __shared__ __attribute__((aligned(16))) bf16 S[24576];   // 48 KB
    int id = blockIdx.x;
    id = (id & 7) * 96 + (id >> 3);          // bijective: 768 = 8 x 96
    const int nt = id % 24, mt = id / 24;
    const int m0 = mt * 128, n0 = nt * 128;
    if (nt < 8) {
        // fold softmax scale (1/8 * log2e) into Q: attn works in log2 domain
        gemm_body<0>(xb, wqkv, bq, q, m0, n0, 0.18033688f, S);
    } else if (nt < 16) {
        gemm_body<0>(xb, wqkv, bk, k, m0, n0, 1.0f, S);
    } else {
        gemm_body<2>(xb, wqkv, bv_, vt, m0, n0, 1.0f, S);
    }
}

__global__ __launch_bounds__(256, 3) void gemm_out(
    const bf16* __restrict__ ab, const bf16* __restrict__ wob,
    const float* __restrict__ bo, float* __restrict__ out) {
    __shared__ __attribute__((aligned(16))) bf16 S[24576];   // 48 KB
    int id = blockIdx.x;
    id = (id & 7) * 32 + (id >> 3);          // bijective: 256 = 8 x 32
    const int m0 = (id >> 3) * 128, n0 = (id & 7) * 128;
    gemm_body<1>(ab, wob, bo, out, m0, n0, 1.0f, S);
}

// ---------------- flash attention v11: barrier-free wave-async ---------------
// 512 blocks (XCD-swizzled), 4 waves. Wave w: q-rows qw*64 (qw=w&1) over kv
// half kvh*1024 (kvh=w>>1), KVBLK=32. Each wave owns a PRIVATE 16 KB LDS
// region (2 bufs x (K 2KB-rows + V^T)) staged by its own global_load_lds and
// gated by its own wave-level vmcnt(8) — ZERO s_barrier in the main loop, so
// the 4 waves drift into anti-phase and MFMA/VALU/LDS pipes interleave across
// waves (R13 showed phase-locked waves leave ~40% issue idle). L on VALU
// (MFMA is now the hotter pipe); kv-half partials are plain sums (no-max
// softmax, R6) combined through LDS at the single final barrier.
__global__ __launch_bounds__(256, 2) void attn(const bf16* __restrict__ Q,
                                               const bf16* __restrict__ K,
                                               const bf16* __restrict__ VT,
                                               bf16* __restrict__ O) {
    // per wave per buf: [0..2047] K tile (32 kv x 64 d, slot^=(r&7) swizzle),
    //                   [2048..4095] V^T tile (64 d x 32 kv, slot^=((d>>1)&3))
    __shared__ __attribute__((aligned(16))) bf16 S[4][2][4096];   // 64 KB

    const int t = threadIdx.x, lane = t & 63, wave = t >> 6;
    const int l31 = lane & 31, hi = lane >> 5;
    const int kvh = wave >> 1;          // kv half
    const int qw  = wave & 1;           // q 64-row sub-block

    int id = blockIdx.x;
    id = (id & 7) * 64 + (id >> 3);     // 8 XCD chunks of 64 blocks (4 heads)
    const int qt = id & 15, h = (id >> 4) & 15, b = id >> 8;

    const bf16* Qb = Q + ((size_t)b * SEQ + qt * 128) * DM + h * DKH;
    const bf16* Kb = K + (size_t)b * SEQ * DM + h * DKH;
    const bf16* Vb = VT + (size_t)((b * NH + h) * DKH) * SEQ;  // [64 d][2048 kv]
    const int kvbase = kvh << 10;

    // Q B-fragments: lane holds Q[q = qw*64 + u*32 + l31][d = c*16 + hi*8 + z]
    bf16x8 qf[2][4];
#pragma unroll
    for (int u = 0; u < 2; ++u)
#pragma unroll
        for (int c = 0; c < 4; ++c)
            qf[u][c] = ld8(Qb + (size_t)(qw * 64 + u * 32 + l31) * DM + c * 16 + hi * 8);

    f32x16 o[2][2] = {};     // [u][dt]: row q=(r&3)+8(r>>2)+4hi, col d=dt*32+l31
    float Lp[2] = {0.f, 0.f};   // per-lane partial L (q=l31's hi-half kv rows)

    bf16* W0 = &S[wave][0][0];
    bf16* W1 = &S[wave][1][0];

    auto STAGE = [&](bf16* dst, int tile) {
        const int kt = kvbase + tile * 32;
#pragma unroll
        for (int i = 0; i < 4; ++i) {          // K: 32 rows x 128B
            const int r = i * 8 + (lane >> 3);
            const int s = (lane & 7) ^ (r & 7);
            gld16(Kb + (size_t)(kt + r) * DM + s * 8, dst + i * 512 + lane * 8);
        }
#pragma unroll
        for (int i = 0; i < 4; ++i) {          // V^T: 64 rows x 64B
            const int d = i * 16 + (lane >> 2);
            const int s = (lane & 3) ^ ((d >> 1) & 3);
            gld16(Vb + (size_t)d * SEQ + kt + s * 8, dst + 2048 + i * 512 + lane * 8);
        }
    };

    auto TILE = [&](const bf16* buf) {
        const bf16* Kt = buf;
        const bf16* Vt = buf + 2048;
        // ---- QK^T: S^T[kv 32][q 32] per u ----
        bf16x8 kf[4];
#pragma unroll
        for (int c = 0; c < 4; ++c) {
            const int slot = l31 * 8 + ((2 * c + hi) ^ (l31 & 7));
            kf[c] = ld8(Kt + slot * 8);
        }
        f32x16 ss0 = {}, ss1 = {};
        __builtin_amdgcn_s_setprio(1);
#pragma unroll
        for (int c = 0; c < 4; ++c) ss0 = mfma32(kf[c], qf[0][c], ss0);
#pragma unroll
        for (int c = 0; c < 4; ++c) ss1 = mfma32(kf[c], qf[1][c], ss1);
        __builtin_amdgcn_s_setprio(0);

        // ---- exp2 + L (VALU) + in-register P A-packs ----
        u32x4 up[2][2];
#pragma unroll
        for (int u = 0; u < 2; ++u) {
            const f32x16& ss = u ? ss1 : ss0;
            float e[16];
#pragma unroll
            for (int r = 0; r < 16; ++r)
                e[r] = __builtin_amdgcn_exp2f(ss[r]);
            Lp[u] += ((e[0] + e[1]) + (e[2] + e[3])) + ((e[4] + e[5]) + (e[6] + e[7]))
                   + ((e[8] + e[9]) + (e[10] + e[11])) + ((e[12] + e[13]) + (e[14] + e[15]));
            unsigned u0 = pkbf(e[0],  e[1]),  u1 = pkbf(e[2],  e[3]);
            unsigned u2 = pkbf(e[4],  e[5]),  u3 = pkbf(e[6],  e[7]);
            unsigned u4 = pkbf(e[8],  e[9]),  u5 = pkbf(e[10], e[11]);
            unsigned u6 = pkbf(e[12], e[13]), u7 = pkbf(e[14], e[15]);
            plswap(u0, u2); plswap(u1, u3);
            plswap(u4, u6); plswap(u5, u7);
            up[u][0] = u32x4{u0, u1, u2, u3};   // kv 0..15  (hi*8 + z)
            up[u][1] = u32x4{u4, u5, u6, u7};   // kv 16..31
        }

        // ---- PV ----
        __builtin_amdgcn_s_setprio(1);
#pragma unroll
        for (int dt = 0; dt < 2; ++dt) {
            const int d = dt * 32 + l31;
#pragma unroll
            for (int kc = 0; kc < 2; ++kc) {
                const int slot = d * 4 + ((kc * 2 + hi) ^ ((d >> 1) & 3));
                const bf16x8 vf = ld8(Vt + slot * 8);
                o[0][dt] = mfma32(__builtin_bit_cast(bf16x8, up[0][kc]), vf, o[0][dt]);
                o[1][dt] = mfma32(__builtin_bit_cast(bf16x8, up[1][kc]), vf, o[1][dt]);
            }
        }
        __builtin_amdgcn_s_setprio(0);
    };

#define GATEW(N) do {                                             \
        asm volatile("s_waitcnt vmcnt(" #N ")" ::: "memory");     \
        __builtin_amdgcn_sched_barrier(0);                        \
    } while (0)

    STAGE(W0, 0);
    STAGE(W1, 1);

#pragma unroll 1
    for (int tt = 0; tt < 30; tt += 2) {
        GATEW(8);                    // tile tt landed (tt+1 in flight)
        TILE(W0);
        __builtin_amdgcn_sched_barrier(0);
        STAGE(W0, tt + 2);
        GATEW(8);                    // tile tt+1 landed
        TILE(W1);
        __builtin_amdgcn_sched_barrier(0);
        if (tt + 3 < 32) STAGE(W1, tt + 3);
    }
    GATEW(8); TILE(W0);              // tile 30
    GATEW(0); TILE(W1);              // tile 31 (full drain)
#undef GATEW

    // ---- combine kv-halves (plain sums) via LDS; single block barrier ------
    __syncthreads();
    float* Xs = (float*)&S[0][0][0];
    if (wave >= 2) {
        float* base = Xs + (wave - 2) * 6144;
#pragma unroll
        for (int u = 0; u < 2; ++u)
#pragma unroll
            for (int dt = 0; dt < 2; ++dt)
#pragma unroll
                for (int g4 = 0; g4 < 4; ++g4) {
                    f32x4 v = {o[u][dt][g4 * 4], o[u][dt][g4 * 4 + 1],
                               o[u][dt][g4 * 4 + 2], o[u][dt][g4 * 4 + 3]};
                    *reinterpret_cast<f32x4*>(
                        base + ((u * 2 + dt) * 4 + g4) * 256 + lane * 4) = v;
                }
        base[16 * 256 + lane] = Lp[0];
        base[16 * 256 + 64 + lane] = Lp[1];
    }
    __syncthreads();
    if (wave < 2) {
        const float* base = Xs + wave * 6144;   // partner = wave + 2
#pragma unroll
        for (int u = 0; u < 2; ++u)
#pragma unroll
            for (int dt = 0; dt < 2; ++dt)
#pragma unroll
                for (int g4 = 0; g4 < 4; ++g4) {
                    f32x4 v = *reinterpret_cast<const f32x4*>(
                        base + ((u * 2 + dt) * 4 + g4) * 256 + lane * 4);
#pragma unroll
                    for (int j = 0; j < 4; ++j) o[u][dt][g4 * 4 + j] += v[j];
                }
        Lp[0] += base[16 * 256 + lane];
        Lp[1] += base[16 * 256 + 64 + lane];

        // ---- epilogue: L(q=l31) = Lp + partner-half; redistribute to rows --
#pragma unroll
        for (int u = 0; u < 2; ++u) {
            const float Lf = Lp[u] + __shfl_xor(Lp[u], 32);
            const float inv = 1.0f / Lf;
            float invr[16];
#pragma unroll
            for (int r = 0; r < 16; ++r)
                invr[r] = __shfl(inv, (r & 3) + 8 * (r >> 2) + 4 * hi);
#pragma unroll
            for (int dt = 0; dt < 2; ++dt)
#pragma unroll
                for (int r = 0; r < 16; ++r) {
                    const int ql = (r & 3) + 8 * (r >> 2) + 4 * hi;
                    O[((size_t)b * SEQ + qt * 128 + qw * 64 + u * 32 + ql) * DM
                      + h * DKH + dt * 32 + l31] = (bf16)(o[u][dt][r] * invr[r]);
                }
        }
    }
}

// ---------------- launch ----------------
extern "C" void kernel_launch(void* const* d_in, const int* in_sizes, int n_in,
                              void* d_out, int out_size, void* d_ws, size_t ws_size,
                              hipStream_t stream) {
    const float* x  = (const float*)d_in[0];
    const float* Wq = (const float*)d_in[1];
    const float* bq = (const float*)d_in[2];
    const float* Wk = (const float*)d_in[3];
    const float* bk = (const float*)d_in[4];
    const float* Wv = (const float*)d_in[5];
    const float* bv = (const float*)d_in[6];
    const float* Wo = (const float*)d_in[7];
    const float* bo = (const float*)d_in[8];
    float* out = (float*)d_out;

    char* ws = (char*)d_ws;
    bf16* xb   = (bf16*)(ws + 0);           // 8 MB
    bf16* wqkv = (bf16*)(ws + 8388608);     // 6 MB concat Wq|Wk|Wv [3072][1024]
    bf16* wqb  = (bf16*)(ws + 8388608);     // rows 0..1023
    bf16* wkb  = (bf16*)(ws + 10485760);    // rows 1024..2047
    bf16* wvb  = (bf16*)(ws + 12582912);    // rows 2048..3071
    bf16* wob  = (bf16*)(ws + 14680064);    // 2 MB
    bf16* qb   = (bf16*)(ws + 16777216);    // 8 MB
    bf16* kb   = (bf16*)(ws + 25165824);    // 8 MB
    bf16* ab   = (bf16*)(ws + 33554432);    // 8 MB  attention output
    bf16* vtb  = (bf16*)(ws + 41943040);    // 8 MB  V^T (written by gemm_qkv)

    cvt_all<<<8192, 256, 0, stream>>>(
        (const float4*)x, (const float4*)Wq, (const float4*)Wk,
        (const float4*)Wv, (const float4*)Wo,
        (ushort4*)xb, (ushort4*)wqb, (ushort4*)wkb, (ushort4*)wvb, (ushort4*)wob);

    gemm_qkv<<<768, 256, 0, stream>>>(xb, wqkv, bq, bk, bv, qb, kb, vtb);

    attn<<<dim3(512), 256, 0, stream>>>(qb, kb, vtb, ab);

    gemm_out<<<256, 256, 0, stream>>>(ab, wob, bo, out);
}

// Round 15
// 103.046 us; speedup vs baseline: 1.0666x; 1.0666x over previous
//
#include <hip/hip_runtime.h>
#include <hip/hip_bf16.h>
#include <cstdint>

typedef __bf16 bf16;
typedef __bf16 bf16x4 __attribute__((ext_vector_type(4)));
typedef __bf16 bf16x8 __attribute__((ext_vector_type(8)));
typedef float f32x4 __attribute__((ext_vector_type(4)));
typedef float f32x16 __attribute__((ext_vector_type(16)));
typedef unsigned int u32x4 __attribute__((ext_vector_type(4)));

#define DM   1024
#define SEQ  2048
#define NH   16
#define DKH  64

__device__ __forceinline__ bf16x8 ld8(const bf16* p) {
    return *reinterpret_cast<const bf16x8*>(p);
}

// async global->LDS, 16B per lane (wave-uniform LDS base + lane*16 layout)
__device__ __forceinline__ void gld16(const void* g, void* lds) {
    __builtin_amdgcn_global_load_lds(
        (__attribute__((address_space(1))) void*)(uintptr_t)g,
        (__attribute__((address_space(3))) void*)(uint32_t)(uintptr_t)lds,
        16, 0, 0);
}

__device__ __forceinline__ f32x4 mfma16(bf16x8 a, bf16x8 b, f32x4 c) {
    return __builtin_amdgcn_mfma_f32_16x16x32_bf16(a, b, c, 0, 0, 0);
}
__device__ __forceinline__ f32x16 mfma32(bf16x8 a, bf16x8 b, f32x16 c) {
    return __builtin_amdgcn_mfma_f32_32x32x16_bf16(a, b, c, 0, 0, 0);
}

// v_cvt_pk_bf16_f32: d[15:0]=bf16(lo), d[31:16]=bf16(hi)
__device__ __forceinline__ unsigned pkbf(float lo, float hi) {
    unsigned r;
    asm("v_cvt_pk_bf16_f32 %0, %1, %2" : "=v"(r) : "v"(lo), "v"(hi));
    return r;
}
// v_permlane32_swap_b32 a, b: a[hi lanes] <-> b[lo lanes]
__device__ __forceinline__ void plswap(unsigned& a, unsigned& b) {
    asm volatile("v_permlane32_swap_b32 %0, %1" : "+v"(a), "+v"(b));
}

// ---------------- fused fp32 -> bf16 casts (x + 4 weights, one launch) -------
__global__ __launch_bounds__(256) void cvt_all(
    const float4* __restrict__ x,  const float4* __restrict__ wq,
    const float4* __restrict__ wk, const float4* __restrict__ wv,
    const float4* __restrict__ wo,
    ushort4* __restrict__ xb,  ushort4* __restrict__ wqb,
    ushort4* __restrict__ wkb, ushort4* __restrict__ wvb,
    ushort4* __restrict__ wob) {
    int i = blockIdx.x * 256 + threadIdx.x;   // 2M float4 total
    const float4* src;
    ushort4* dst;
    int off;
    if (i < 1048576) {
        src = x; dst = xb; off = i;
    } else {
        int r = i - 1048576;
        int sel = r >> 18;          // 4 weight regions of 256K float4
        off = r & 262143;
        src = sel == 0 ? wq : sel == 1 ? wk : sel == 2 ? wv : wo;
        dst = sel == 0 ? wqb : sel == 1 ? wkb : sel == 2 ? wvb : wob;
    }
    float4 f = src[off];
    ushort4 u;
    u.x = __builtin_bit_cast(unsigned short, (bf16)f.x);
    u.y = __builtin_bit_cast(unsigned short, (bf16)f.y);
    u.z = __builtin_bit_cast(unsigned short, (bf16)f.z);
    u.w = __builtin_bit_cast(unsigned short, (bf16)f.w);
    dst[off] = u;
}

// ---------------- fused QKV GEMM v2: 256x256 tile, BK=64, 8-phase pipeline ---
// 8 waves (2M x 4N), 2 dbufs (64 KB each), 4 phases per K-tile. Each phase:
// counted-vmcnt gate + barrier -> stage 2 quarter-tiles of tile t+1 into the
// other dbuf -> ds_read A-frags (m-quadrant; B-frags at phase 0) -> 16 MFMA.
// Gate derivation (FIFO, 2 loads/thread/phase, stage order B01 B23 A02 A13):
// q0 needs B-own + Aq0/q2 (issued <= t-1.q2) -> vmcnt(2); q1 -> 4; q2 needs
// Aq1/q3 (t-1.q3) -> 4; q3 -> 6. Last tile drains 2,2,0,0.
__global__ __launch_bounds__(512, 1) void gemm_qkv(
    const bf16* __restrict__ xb, const bf16* __restrict__ wqkv,
    const float* __restrict__ bq, const float* __restrict__ bk,
    const float* __restrict__ bv_,
    bf16* __restrict__ q_, bf16* __restrict__ k_, bf16* __restrict__ vt) {
    // dbuf d: A @ d*32768 (256x64), B @ d*32768+16384. Epilogue: 8 x 8704/wave.
    __shared__ __attribute__((aligned(16))) bf16 S[69632];   // 139,264 B

    const int t = threadIdx.x, lane = t & 63;
    const int r16 = lane & 15, grp = lane >> 4;
    const int wave = t >> 6;
    const int wr = (wave >> 2) * 128;     // M offset (2 halves)
    const int wc = (wave & 3) * 64;       // N offset (4 quarters)

    int id = blockIdx.x;
    id = (id & 7) * 24 + (id >> 3);       // bijective: 192 = 8 x 24
    const int nt = id % 12, mt = id / 12;
    const int m0 = mt * 256, n0 = nt * 256;

    f32x4 acc[8][4] = {};
    const int srow = t >> 3, scol = t & 7;

    // stage one quarter (64 rows x 64 cols) of A (which=0) or B (which=1)
    auto STQ = [&](int dbuf, int tile, int which, int qq) {
        const int row = qq * 64 + srow;
        const int cs = (scol ^ (row & 7)) * 8;     // pre-swizzled source col
        const bf16* src = which
            ? wqkv + (size_t)(n0 + row) * DM + tile * 64 + cs
            : xb   + (size_t)(m0 + row) * DM + tile * 64 + cs;
        gld16(src, &S[dbuf * 32768 + which * 16384 + qq * 4096 + t * 8]);
    };

    bf16x8 bfr[4][2];

#define GATE(N) do {                                              \
        asm volatile("s_waitcnt vmcnt(" #N ")" ::: "memory");     \
        __builtin_amdgcn_sched_barrier(0);                        \
        __builtin_amdgcn_s_barrier();                             \
        __builtin_amdgcn_sched_barrier(0);                        \
    } while (0)

#define PHASE(d, q, stg, dostg) do {                                          \
        if (dostg) {                                                          \
            if ((q) == 0)      { STQ((d) ^ 1, stg, 1, 0); STQ((d) ^ 1, stg, 1, 1); } \
            else if ((q) == 1) { STQ((d) ^ 1, stg, 1, 2); STQ((d) ^ 1, stg, 1, 3); } \
            else if ((q) == 2) { STQ((d) ^ 1, stg, 0, 0); STQ((d) ^ 1, stg, 0, 2); } \
            else               { STQ((d) ^ 1, stg, 0, 1); STQ((d) ^ 1, stg, 0, 3); } \
        }                                                                     \
        const bf16* Ab = &S[(d) * 32768];                                     \
        const bf16* Bb = &S[(d) * 32768 + 16384];                             \
        if ((q) == 0) {                                                       \
            _Pragma("unroll")                                                 \
            for (int n = 0; n < 4; ++n) {                                     \
                const int row = wc + n * 16 + r16;                            \
                bfr[n][0] = ld8(&Bb[row * 64 + ((grp ^ (row & 7)) * 8)]);     \
                bfr[n][1] = ld8(&Bb[row * 64 + (((4 + grp) ^ (row & 7)) * 8)]); \
            }                                                                 \
        }                                                                     \
        bf16x8 af0k0, af0k1, af1k0, af1k1;                                    \
        { const int row = wr + ((q) * 2) * 16 + r16;                          \
          af0k0 = ld8(&Ab[row * 64 + ((grp ^ (row & 7)) * 8)]);               \
          af0k1 = ld8(&Ab[row * 64 + (((4 + grp) ^ (row & 7)) * 8)]); }       \
        { const int row = wr + ((q) * 2 + 1) * 16 + r16;                      \
          af1k0 = ld8(&Ab[row * 64 + ((grp ^ (row & 7)) * 8)]);               \
          af1k1 = ld8(&Ab[row * 64 + (((4 + grp) ^ (row & 7)) * 8)]); }       \
        __builtin_amdgcn_s_setprio(1);                                        \
        _Pragma("unroll")                                                     \
        for (int n = 0; n < 4; ++n) {                                         \
            acc[(q) * 2][n]     = mfma16(af0k0, bfr[n][0], acc[(q) * 2][n]);  \
            acc[(q) * 2][n]     = mfma16(af0k1, bfr[n][1], acc[(q) * 2][n]);  \
            acc[(q) * 2 + 1][n] = mfma16(af1k0, bfr[n][0], acc[(q) * 2 + 1][n]); \
            acc[(q) * 2 + 1][n] = mfma16(af1k1, bfr[n][1], acc[(q) * 2 + 1][n]); \
        }                                                                     \
        __builtin_amdgcn_s_setprio(0);                                        \
    } while (0)

    // prologue: tile 0 -> dbuf 0, issue order B01 B23 A0 A2 A1 A3
    STQ(0, 0, 1, 0); STQ(0, 0, 1, 1); STQ(0, 0, 1, 2); STQ(0, 0, 1, 3);
    STQ(0, 0, 0, 0); STQ(0, 0, 0, 2); STQ(0, 0, 0, 1); STQ(0, 0, 0, 3);

#pragma unroll 1
    for (int g = 0; g < 7; ++g) {          // tiles 0..13
        const int t0 = 2 * g;
        GATE(2); PHASE(0, 0, t0 + 1, true);
        GATE(4); PHASE(0, 1, t0 + 1, true);
        GATE(4); PHASE(0, 2, t0 + 1, true);
        GATE(6); PHASE(0, 3, t0 + 1, true);
        GATE(2); PHASE(1, 0, t0 + 2, true);
        GATE(4); PHASE(1, 1, t0 + 2, true);
        GATE(4); PHASE(1, 2, t0 + 2, true);
        GATE(6); PHASE(1, 3, t0 + 2, true);
    }
    // tile 14 (dbuf 0), staging tile 15
    GATE(2); PHASE(0, 0, 15, true);
    GATE(4); PHASE(0, 1, 15, true);
    GATE(4); PHASE(0, 2, 15, true);
    GATE(6); PHASE(0, 3, 15, true);
    // tile 15 (dbuf 1), drain
    GATE(2); PHASE(1, 0, 0, false);
    GATE(2); PHASE(1, 1, 0, false);
    GATE(0); PHASE(1, 2, 0, false);
    GATE(0); PHASE(1, 3, 0, false);
#undef GATE
#undef PHASE

    // ---- epilogue ----
    if (n0 < 2048) {
        const float scale = (n0 < 1024) ? 0.18033688f : 1.0f;  // Q: 1/8*log2e
        bf16* out = (n0 < 1024) ? q_ : k_;
        const float* bias = (n0 < 1024) ? bq : bk;
        const int nc0 = n0 & 1023;
#pragma unroll
        for (int n = 0; n < 4; ++n) {
            const int col = nc0 + wc + n * 16 + r16;
            const float bvv = bias[col];
#pragma unroll
            for (int m = 0; m < 8; ++m) {
                const int row = m0 + wr + m * 16 + grp * 4;
#pragma unroll
                for (int j = 0; j < 4; ++j)
                    out[(size_t)(row + j) * DM + col] =
                        (bf16)((acc[m][n][j] + bvv) * scale);
            }
        }
    } else {
        // V^T: transpose this wave's 128tok x 64dim frag via private LDS slice
        const int nc0 = n0 - 2048;
        const int b = m0 >> 11;
        const int s0 = (m0 & 2047) + wr;
        __syncthreads();
        bf16* Tw = &S[wave * 8704];          // 64 dim-rows x 136 stride
#pragma unroll
        for (int n = 0; n < 4; ++n) {
            const int dl = n * 16 + r16;     // local dim 0..63
            const float bvv = bv_[nc0 + wc + dl];
#pragma unroll
            for (int m = 0; m < 8; ++m) {
                bf16x4 w4 = {(bf16)(acc[m][n][0] + bvv), (bf16)(acc[m][n][1] + bvv),
                             (bf16)(acc[m][n][2] + bvv), (bf16)(acc[m][n][3] + bvv)};
                *reinterpret_cast<bf16x4*>(&Tw[dl * 136 + m * 16 + grp * 4]) = w4;
            }
        }
        asm volatile("" ::: "memory");
#pragma unroll
        for (int dd = 0; dd < 8; ++dd) {
            const int dim = dd * 8 + (lane >> 3);    // local dim
            const int col = nc0 + wc + dim;
            bf16* dst = vt + ((size_t)(b * NH + (col >> 6)) * DKH + (col & 63)) * SEQ + s0;
#pragma unroll
            for (int cc = 0; cc < 2; ++cc) {
                const int c = (lane & 7) + cc * 8;   // 8-token chunk
                bf16x8 v = ld8(&Tw[dim * 136 + c * 8]);
                *reinterpret_cast<bf16x8*>(dst + c * 8) = v;
            }
        }
    }
}

// ---------------- output GEMM: 128x128 tile, BK=32, 3-buffer counted-vmcnt ---
__global__ __launch_bounds__(256, 3) void gemm_out(
    const bf16* __restrict__ A, const bf16* __restrict__ W,
    const float* __restrict__ bias, float* __restrict__ out) {
    constexpr int BK = 32;
    __shared__ __attribute__((aligned(16))) bf16 S[24576];   // 48 KB
    const int t    = threadIdx.x;
    const int lane = t & 63;
    const int r16  = lane & 15, grp = lane >> 4;
    const int wave = t >> 6;
    const int wr   = (wave >> 1) * 64;
    const int wc   = (wave & 1) * 64;
    int id = blockIdx.x;
    id = (id & 7) * 32 + (id >> 3);          // bijective: 256 = 8 x 32
    const int m0 = (id >> 3) * 128, n0 = (id & 7) * 128;

    f32x4 acc[4][4] = {};
    const int srow = t >> 2, scol = t & 3;

    auto STAGE = [&](int buf, int kt) {
#pragma unroll
        for (int i = 0; i < 2; ++i) {
            const int row = i * 64 + srow;
            const int cs = (scol ^ (row & 3)) * 8;
            gld16(A + (size_t)(m0 + row) * DM + kt * BK + cs,
                  &S[buf * 8192 + i * 2048 + t * 8]);
            gld16(W + (size_t)(n0 + row) * DM + kt * BK + cs,
                  &S[buf * 8192 + 4096 + i * 2048 + t * 8]);
        }
    };

    STAGE(0, 0);
    STAGE(1, 1);

#pragma unroll
    for (int kt = 0; kt < 32; ++kt) {
        if (kt == 31) { asm volatile("s_waitcnt vmcnt(0)" ::: "memory"); }
        else          { asm volatile("s_waitcnt vmcnt(4)" ::: "memory"); }
        __builtin_amdgcn_sched_barrier(0);
        __builtin_amdgcn_s_barrier();
        __builtin_amdgcn_sched_barrier(0);

        if (kt < 30) STAGE((kt + 2) % 3, kt + 2);

        const bf16* Ab = &S[(kt % 3) * 8192];
        const bf16* Bb = Ab + 4096;
        bf16x8 af[4], bfr[4];
#pragma unroll
        for (int m = 0; m < 4; ++m) {
            const int row = wr + m * 16 + r16;
            af[m] = ld8(&Ab[row * BK + ((grp ^ (row & 3)) * 8)]);
        }
#pragma unroll
        for (int n = 0; n < 4; ++n) {
            const int row = wc + n * 16 + r16;
            bfr[n] = ld8(&Bb[row * BK + ((grp ^ (row & 3)) * 8)]);
        }
        __builtin_amdgcn_s_setprio(1);
#pragma unroll
        for (int m = 0; m < 4; ++m)
#pragma unroll
            for (int n = 0; n < 4; ++n)
                acc[m][n] = mfma16(af[m], bfr[n], acc[m][n]);
        __builtin_amdgcn_s_setprio(0);
    }

#pragma unroll
    for (int n = 0; n < 4; ++n) {
        const int col = n0 + wc + n * 16 + r16;
        const float bvv = bias[col];
#pragma unroll
        for (int m = 0; m < 4; ++m) {
            const int row = m0 + wr + m * 16 + grp * 4;
#pragma unroll
            for (int j = 0; j < 4; ++j)
                out[(size_t)(row + j) * DM + col] = acc[m][n][j] + bvv;
        }
    }
}

// ---------------- flash attention v10 (R13 best: 50.0 us): kv-split waves ----
__global__ __launch_bounds__(256, 2) void attn(const bf16* __restrict__ Q,
                                               const bf16* __restrict__ K,
                                               const bf16* __restrict__ VT,
                                               bf16* __restrict__ O) {
    // S[half][buf]: [0..4095] = K tile (64 kv x 64 d), [4096..8191] = V^T tile
    __shared__ __attribute__((aligned(16))) bf16 S[2][2][8192];   // 64 KB

    const int t = threadIdx.x, lane = t & 63, wave = t >> 6;
    const int l31 = lane & 31, hi = lane >> 5;
    const int kvh = wave >> 1;          // this wave's kv half
    const int qw  = wave & 1;           // this wave's q 64-row sub-block

    int id = blockIdx.x;
    id = (id & 7) * 64 + (id >> 3);     // 8 XCD chunks of 64 blocks (4 heads)
    const int qt = id & 15, h = (id >> 4) & 15, b = id >> 8;

    const bf16* Qb = Q + ((size_t)b * SEQ + qt * 128) * DM + h * DKH;
    const bf16* Kb = K + (size_t)b * SEQ * DM + h * DKH;
    const bf16* Vb = VT + (size_t)((b * NH + h) * DKH) * SEQ;  // [64 d][2048 kv]

    bf16x8 qf[2][4];
#pragma unroll
    for (int u = 0; u < 2; ++u)
#pragma unroll
        for (int c = 0; c < 4; ++c)
            qf[u][c] = ld8(Qb + (size_t)(qw * 64 + u * 32 + l31) * DM + c * 16 + hi * 8);

    const bf16 one = (bf16)1.0f;
    const bf16x8 ones8 = {one, one, one, one, one, one, one, one};

    f32x16 o[2][2] = {};     // [u][dt]
    f32x16 ol[2] = {};       // [u] L via mfma(P, ones)

    const int sr = t >> 3, scs = t & 7;

    auto STAGE = [&](int buf, int step) {
#pragma unroll
        for (int hf = 0; hf < 2; ++hf) {
            const int kt = hf * 1024 + step * 64;
            bf16* Kd = &S[hf][buf][0];
            bf16* Vd = &S[hf][buf][4096];
#pragma unroll
            for (int i = 0; i < 2; ++i) {
                const int r = i * 32 + sr;
                const int cs = (scs ^ (r & 7)) * 8;
                gld16(Kb + (size_t)(kt + r) * DM + cs, Kd + i * 2048 + t * 8);
                gld16(Vb + (size_t)r * SEQ + kt + cs, Vd + i * 2048 + t * 8);
            }
        }
    };

    auto TILE = [&](const bf16* KsB, const bf16* VsB) {
        u32x4 up[2][4];
#pragma unroll
        for (int sub = 0; sub < 2; ++sub) {
            const int krow = sub * 32 + l31;
            const int ksw  = krow & 7;
            bf16x8 kf[4];
#pragma unroll
            for (int c = 0; c < 4; ++c)
                kf[c] = ld8(&KsB[krow * 64 + (((c * 2 + hi) ^ ksw) * 8)]);
            f32x16 ss0 = {}, ss1 = {};
            __builtin_amdgcn_s_setprio(1);
#pragma unroll
            for (int c = 0; c < 4; ++c) ss0 = mfma32(kf[c], qf[0][c], ss0);
#pragma unroll
            for (int c = 0; c < 4; ++c) ss1 = mfma32(kf[c], qf[1][c], ss1);
            __builtin_amdgcn_s_setprio(0);
#pragma unroll
            for (int u = 0; u < 2; ++u) {
                const f32x16& ss = u ? ss1 : ss0;
                float e[16];
#pragma unroll
                for (int r = 0; r < 16; ++r)
                    e[r] = __builtin_amdgcn_exp2f(ss[r]);
                unsigned u0 = pkbf(e[0],  e[1]),  u1 = pkbf(e[2],  e[3]);
                unsigned u2 = pkbf(e[4],  e[5]),  u3 = pkbf(e[6],  e[7]);
                unsigned u4 = pkbf(e[8],  e[9]),  u5 = pkbf(e[10], e[11]);
                unsigned u6 = pkbf(e[12], e[13]), u7 = pkbf(e[14], e[15]);
                plswap(u0, u2); plswap(u1, u3);
                plswap(u4, u6); plswap(u5, u7);
                up[u][sub * 2]     = u32x4{u0, u1, u2, u3};
                up[u][sub * 2 + 1] = u32x4{u4, u5, u6, u7};
            }
        }

        __builtin_amdgcn_s_setprio(1);
#pragma unroll
        for (int dt = 0; dt < 2; ++dt) {
            const int vrow = dt * 32 + l31;
            const int vsw  = vrow & 7;
#pragma unroll
            for (int kc = 0; kc < 4; ++kc) {
                const bf16x8 vf = ld8(&VsB[vrow * 64 + (((kc * 2 + hi) ^ vsw) * 8)]);
                o[0][dt] = mfma32(__builtin_bit_cast(bf16x8, up[0][kc]), vf, o[0][dt]);
                o[1][dt] = mfma32(__builtin_bit_cast(bf16x8, up[1][kc]), vf, o[1][dt]);
            }
        }
#pragma unroll
        for (int kc = 0; kc < 4; ++kc) {
            ol[0] = mfma32(__builtin_bit_cast(bf16x8, up[0][kc]), ones8, ol[0]);
            ol[1] = mfma32(__builtin_bit_cast(bf16x8, up[1][kc]), ones8, ol[1]);
        }
        __builtin_amdgcn_s_setprio(0);
    };

#define GATE(N) do {                                              \
        asm volatile("s_waitcnt vmcnt(" #N ")" ::: "memory");     \
        __builtin_amdgcn_sched_barrier(0);                        \
    } while (0)
#define BAR() do {                                                \
        __builtin_amdgcn_sched_barrier(0);                        \
        __builtin_amdgcn_s_barrier();                             \
        __builtin_amdgcn_sched_barrier(0);                        \
    } while (0)

    STAGE(0, 0);
    STAGE(1, 1);

    GATE(8); TILE(&S[kvh][0][0], &S[kvh][0][4096]);     // step 0
#pragma unroll 1
    for (int g = 0; g < 7; ++g) {                        // steps 1..14
        BAR(); STAGE(0, 2 * g + 2);
        GATE(8); TILE(&S[kvh][1][0], &S[kvh][1][4096]);
        BAR(); STAGE(1, 2 * g + 3);
        GATE(8); TILE(&S[kvh][0][0], &S[kvh][0][4096]);
    }
    BAR();
    GATE(0); TILE(&S[kvh][1][0], &S[kvh][1][4096]);      // step 15
#undef GATE
#undef BAR

    // ---- combine kv-halves: plain sums (no-max softmax) via dead LDS -------
    __syncthreads();
    float* Xs = (float*)&S[0][0][0];
    if (wave >= 2) {
        float* base = Xs + (wave - 2) * 6144;
#pragma unroll
        for (int u = 0; u < 2; ++u)
#pragma unroll
            for (int dt = 0; dt < 2; ++dt)
#pragma unroll
                for (int g4 = 0; g4 < 4; ++g4) {
                    f32x4 v = {o[u][dt][g4 * 4], o[u][dt][g4 * 4 + 1],
                               o[u][dt][g4 * 4 + 2], o[u][dt][g4 * 4 + 3]};
                    *reinterpret_cast<f32x4*>(
                        base + ((u * 2 + dt) * 4 + g4) * 256 + lane * 4) = v;
                }
#pragma unroll
        for (int u = 0; u < 2; ++u)
#pragma unroll
            for (int g4 = 0; g4 < 4; ++g4) {
                f32x4 v = {ol[u][g4 * 4], ol[u][g4 * 4 + 1],
                           ol[u][g4 * 4 + 2], ol[u][g4 * 4 + 3]};
                *reinterpret_cast<f32x4*>(
                    base + (16 + u * 4 + g4) * 256 + lane * 4) = v;
            }
    }
    __syncthreads();
    if (wave < 2) {
        const float* base = Xs + wave * 6144;
#pragma unroll
        for (int u = 0; u < 2; ++u)
#pragma unroll
            for (int dt = 0; dt < 2; ++dt)
#pragma unroll
                for (int g4 = 0; g4 < 4; ++g4) {
                    f32x4 v = *reinterpret_cast<const f32x4*>(
                        base + ((u * 2 + dt) * 4 + g4) * 256 + lane * 4);
#pragma unroll
                    for (int j = 0; j < 4; ++j) o[u][dt][g4 * 4 + j] += v[j];
                }
#pragma unroll
        for (int u = 0; u < 2; ++u)
#pragma unroll
            for (int g4 = 0; g4 < 4; ++g4) {
                f32x4 v = *reinterpret_cast<const f32x4*>(
                    base + (16 + u * 4 + g4) * 256 + lane * 4);
#pragma unroll
                for (int j = 0; j < 4; ++j) ol[u][g4 * 4 + j] += v[j];
            }

#pragma unroll
        for (int u = 0; u < 2; ++u) {
            float inv[16];
#pragma unroll
            for (int r = 0; r < 16; ++r) inv[r] = 1.0f / ol[u][r];
#pragma unroll
            for (int dt = 0; dt < 2; ++dt)
#pragma unroll
                for (int r = 0; r < 16; ++r) {
                    const int ql = (r & 3) + 8 * (r >> 2) + 4 * hi;
                    O[((size_t)b * SEQ + qt * 128 + qw * 64 + u * 32 + ql) * DM
                      + h * DKH + dt * 32 + l31] = (bf16)(o[u][dt][r] * inv[r]);
                }
        }
    }
}

// ---------------- launch ----------------
extern "C" void kernel_launch(void* const* d_in, const int* in_sizes, int n_in,
                              void* d_out, int out_size, void* d_ws, size_t ws_size,
                              hipStream_t stream) {
    const float* x  = (const float*)d_in[0];
    const float* Wq = (const float*)d_in[1];
    const float* bq = (const float*)d_in[2];
    const float* Wk = (const float*)d_in[3];
    const float* bk = (const float*)d_in[4];
    const float* Wv = (const float*)d_in[5];
    const float* bv = (const float*)d_in[6];
    const float* Wo = (const float*)d_in[7];
    const float* bo = (const float*)d_in[8];
    float* out = (float*)d_out;

    char* ws = (char*)d_ws;
    bf16* xb   = (bf16*)(ws + 0);           // 8 MB
    bf16* wqkv = (bf16*)(ws + 8388608);     // 6 MB concat Wq|Wk|Wv [3072][1024]
    bf16* wqb  = (bf16*)(ws + 8388608);     // rows 0..1023
    bf16* wkb  = (bf16*)(ws + 10485760);    // rows 1024..2047
    bf16* wvb  = (bf16*)(ws + 12582912);    // rows 2048..3071
    bf16* wob  = (bf16*)(ws + 14680064);    // 2 MB
    bf16* qb   = (bf16*)(ws + 16777216);    // 8 MB
    bf16* kb   = (bf16*)(ws + 25165824);    // 8 MB
    bf16* ab   = (bf16*)(ws + 33554432);    // 8 MB  attention output
    bf16* vtb  = (bf16*)(ws + 41943040);    // 8 MB  V^T (written by gemm_qkv)

    cvt_all<<<8192, 256, 0, stream>>>(
        (const float4*)x, (const float4*)Wq, (const float4*)Wk,
        (const float4*)Wv, (const float4*)Wo,
        (ushort4*)xb, (ushort4*)wqb, (ushort4*)wkb, (ushort4*)wvb, (ushort4*)wob);

    gemm_qkv<<<192, 512, 0, stream>>>(xb, wqkv, bq, bk, bv, qb, kb, vtb);

    attn<<<dim3(512), 256, 0, stream>>>(qb, kb, vtb, ab);

    gemm_out<<<256, 256, 0, stream>>>(ab, wob, bo, out);
}